// Round 1
// baseline (154.405 us; speedup 1.0000x reference)
//
#include <hip/hip_runtime.h>

typedef short bf16x8 __attribute__((ext_vector_type(8)));
typedef float f32x4 __attribute__((ext_vector_type(4)));

#define D 128
#define NROW 98304          // 3 groups * 64 mc * 512 rows
#define X_ELEMS ((size_t)NROW * D)          // bf16 elements in ws
#define INV_COUNT 5.9604644775390625e-08f   // 1 / (64*512*512)

__device__ __forceinline__ unsigned short f2bf(float f) {
    unsigned u = __float_as_uint(f);
    u += 0x7FFFu + ((u >> 16) & 1u);        // round-to-nearest-even
    return (unsigned short)(u >> 16);
}
__device__ __forceinline__ float bf2f(unsigned short h) {
    return __uint_as_float(((unsigned)h) << 16);
}

// One wave per (g,m,n) row: X = mu + sigma*eps -> bf16, plus fp32 sum(x_bf16^2).
__global__ __launch_bounds__(256) void prep_kernel(
    const float* __restrict__ mu, const float* __restrict__ sigma,
    const float* __restrict__ epsA, const float* __restrict__ epsB,
    const float* __restrict__ epsC,
    unsigned short* __restrict__ Xb, float* __restrict__ sumsq)
{
    int row  = blockIdx.x * 4 + (threadIdx.x >> 6);   // 0..NROW-1
    int lane = threadIdx.x & 63;
    int n  = row & 511;
    int gm = row >> 9;        // g*64 + m
    int g  = gm >> 6;
    int m  = gm & 63;
    const float* eps = (g == 0) ? epsA : (g == 1) ? epsB : epsC;
    const float2* e2 = (const float2*)(eps + ((size_t)m * 512 + n) * D);
    const float2* u2 = (const float2*)(mu    + ((size_t)(g * 512 + n)) * D);
    const float2* s2 = (const float2*)(sigma + ((size_t)(g * 512 + n)) * D);
    float2 e = e2[lane], u = u2[lane], s = s2[lane];
    unsigned short b0 = f2bf(fmaf(s.x, e.x, u.x));
    unsigned short b1 = f2bf(fmaf(s.y, e.y, u.y));
    float f0 = bf2f(b0), f1 = bf2f(b1);
    float ss = f0 * f0 + f1 * f1;
    ((ushort2*)(Xb + (size_t)row * D))[lane] = make_ushort2(b0, b1);
    #pragma unroll
    for (int o = 32; o > 0; o >>= 1) ss += __shfl_down(ss, o, 64);
    if (lane == 0) sumsq[row] = ss;
}

// One block = one 128x128 tile of one distance matrix for one mc sample.
// grid = (16 tiles, 64 mc, 3 dists). d2 = x2 + y2 - 2*(X Y^T) via bf16 MFMA.
__global__ __launch_bounds__(256, 2) void dist_kernel(
    const unsigned short* __restrict__ Xb, const float* __restrict__ sumsq,
    float* __restrict__ out)
{
    const int tn = blockIdx.x >> 2, tk = blockIdx.x & 3;
    const int m = blockIdx.y;
    const int dist = blockIdx.z;
    // dist 0: AC (x=A=0, y=C=2); dist 1: BA (x=B=1, y=A=0); dist 2: BC (x=B=1, y=C=2)
    const int gx = (dist == 0) ? 0 : 1;
    const int gy = (dist == 1) ? 0 : 2;

    const unsigned short* Xa = Xb + (((size_t)(gx * 64 + m)) * 512 + tn * 128) * D;
    const unsigned short* Xc = Xb + (((size_t)(gy * 64 + m)) * 512 + tk * 128) * D;

    __shared__ unsigned short lds[2 * 128 * 128];   // 64 KB exactly
    unsigned short* As = lds;
    unsigned short* Bs = lds + 128 * 128;

    const int t = threadIdx.x;
    // Stage both 128x128 bf16 tiles. 16B granules, XOR-swizzle granule index by
    // (row&7) so ds_read_b128 of 16 consecutive rows is only 2-way bank-aliased.
    #pragma unroll
    for (int i = 0; i < 8; i++) {
        int c = t + i * 256;          // granule 0..2047
        int row = c >> 4, gidx = c & 15;
        int sg = gidx ^ (row & 7);
        *(uint4*)&As[row * D + sg * 8] = *(const uint4*)&Xa[row * D + gidx * 8];
        *(uint4*)&Bs[row * D + sg * 8] = *(const uint4*)&Xc[row * D + gidx * 8];
    }
    __syncthreads();

    const int wave = t >> 6, lane = t & 63;
    const int wr = (wave >> 1) * 64;      // wave's 64x64 quadrant
    const int wc = (wave & 1) * 64;
    const int l15 = lane & 15, quad = lane >> 4;

    f32x4 acc[4][4] = {};
    #pragma unroll
    for (int ks = 0; ks < 4; ks++) {              // K = 128 in steps of 32
        const int gidx = ks * 4 + quad;           // granule along the row
        bf16x8 a[4], b[4];
        #pragma unroll
        for (int fr = 0; fr < 4; fr++) {
            int row = wr + fr * 16 + l15;
            a[fr] = *(bf16x8*)&As[row * D + (gidx ^ (row & 7)) * 8];
        }
        #pragma unroll
        for (int fc = 0; fc < 4; fc++) {
            int row = wc + fc * 16 + l15;
            b[fc] = *(bf16x8*)&Bs[row * D + (gidx ^ (row & 7)) * 8];
        }
        #pragma unroll
        for (int fr = 0; fr < 4; fr++)
            #pragma unroll
            for (int fc = 0; fc < 4; fc++)
                acc[fr][fc] = __builtin_amdgcn_mfma_f32_16x16x32_bf16(
                    a[fr], b[fc], acc[fr][fc], 0, 0, 0);
    }

    // Epilogue: d2 = x2 + y2 - 2*dot; C layout: col = lane&15, row = quad*4 + i
    const float* ssx = sumsq + ((size_t)(gx * 64 + m)) * 512 + tn * 128;
    const float* ssy = sumsq + ((size_t)(gy * 64 + m)) * 512 + tk * 128;
    float x2v[16], y2v[4];
    #pragma unroll
    for (int fr = 0; fr < 4; fr++)
        #pragma unroll
        for (int i = 0; i < 4; i++)
            x2v[fr * 4 + i] = ssx[wr + fr * 16 + quad * 4 + i];
    #pragma unroll
    for (int fc = 0; fc < 4; fc++)
        y2v[fc] = ssy[wc + fc * 16 + l15];

    float lsum = 0.f;
    #pragma unroll
    for (int fr = 0; fr < 4; fr++) {
        #pragma unroll
        for (int fc = 0; fc < 4; fc++) {
            #pragma unroll
            for (int i = 0; i < 4; i++) {
                float d2 = fmaxf(x2v[fr * 4 + i] + y2v[fc] - 2.f * acc[fr][fc][i],
                                 1e-12f);
                if (dist == 0) {
                    lsum += d2;                       // mean(dAC^2)
                } else {
                    float td = fmaxf(2.f - sqrtf(d2), 0.f);   // relu(M - d)
                    lsum += td * td;
                }
            }
        }
    }

    #pragma unroll
    for (int o = 32; o > 0; o >>= 1) lsum += __shfl_down(lsum, o, 64);
    __syncthreads();                      // tiles no longer needed; reuse LDS
    float* red = (float*)lds;
    if (lane == 0) red[wave] = lsum;
    __syncthreads();
    if (t == 0) {
        float bs = red[0] + red[1] + red[2] + red[3];
        atomicAdd(out, bs * INV_COUNT);
    }
}

extern "C" void kernel_launch(void* const* d_in, const int* in_sizes, int n_in,
                              void* d_out, int out_size, void* d_ws, size_t ws_size,
                              hipStream_t stream) {
    const float* mu    = (const float*)d_in[0];
    const float* sigma = (const float*)d_in[1];
    const float* epsA  = (const float*)d_in[2];
    const float* epsB  = (const float*)d_in[3];
    const float* epsC  = (const float*)d_in[4];
    float* out = (float*)d_out;

    unsigned short* Xb = (unsigned short*)d_ws;              // 25.17 MB bf16
    float* sumsq = (float*)((char*)d_ws + X_ELEMS * sizeof(unsigned short)); // 0.39 MB

    hipMemsetAsync(out, 0, sizeof(float) * out_size, stream);

    prep_kernel<<<NROW / 4, 256, 0, stream>>>(mu, sigma, epsA, epsB, epsC, Xb, sumsq);

    dim3 grid(16, 64, 3);
    dist_kernel<<<grid, 256, 0, stream>>>(Xb, sumsq, out);
}

// Round 2
// 150.486 us; speedup vs baseline: 1.0260x; 1.0260x over previous
//
#include <hip/hip_runtime.h>

typedef short bf16x8 __attribute__((ext_vector_type(8)));
typedef float f32x4 __attribute__((ext_vector_type(4)));

#define D 128
#define NROW 98304          // 3 groups * 64 mc * 512 rows
#define X_ELEMS ((size_t)NROW * D)          // bf16 elements in ws
#define INV_COUNT 5.9604644775390625e-08f   // 1 / (64*512*512)

__device__ __forceinline__ unsigned short f2bf(float f) {
    unsigned u = __float_as_uint(f);
    u += 0x7FFFu + ((u >> 16) & 1u);        // round-to-nearest-even
    return (unsigned short)(u >> 16);
}
__device__ __forceinline__ float bf2f(unsigned short h) {
    return __uint_as_float(((unsigned)h) << 16);
}

// One wave per (g,m,n) row: X = mu + sigma*eps -> bf16, plus fp32 sum(x_bf16^2).
// Block 0 thread 0 also zeroes the output accumulator (dist launches after).
__global__ __launch_bounds__(256) void prep_kernel(
    const float* __restrict__ mu, const float* __restrict__ sigma,
    const float* __restrict__ epsA, const float* __restrict__ epsB,
    const float* __restrict__ epsC,
    unsigned short* __restrict__ Xb, float* __restrict__ sumsq,
    float* __restrict__ out)
{
    if (blockIdx.x == 0 && threadIdx.x == 0) out[0] = 0.f;
    int row  = blockIdx.x * 4 + (threadIdx.x >> 6);   // 0..NROW-1
    int lane = threadIdx.x & 63;
    int n  = row & 511;
    int gm = row >> 9;        // g*64 + m
    int g  = gm >> 6;
    int m  = gm & 63;
    const float* eps = (g == 0) ? epsA : (g == 1) ? epsB : epsC;
    const float2* e2 = (const float2*)(eps + ((size_t)m * 512 + n) * D);
    const float2* u2 = (const float2*)(mu    + ((size_t)(g * 512 + n)) * D);
    const float2* s2 = (const float2*)(sigma + ((size_t)(g * 512 + n)) * D);
    float2 e = e2[lane], u = u2[lane], s = s2[lane];
    unsigned short b0 = f2bf(fmaf(s.x, e.x, u.x));
    unsigned short b1 = f2bf(fmaf(s.y, e.y, u.y));
    float f0 = bf2f(b0), f1 = bf2f(b1);
    float ss = f0 * f0 + f1 * f1;
    ((ushort2*)(Xb + (size_t)row * D))[lane] = make_ushort2(b0, b1);
    #pragma unroll
    for (int o = 32; o > 0; o >>= 1) ss += __shfl_down(ss, o, 64);
    if (lane == 0) sumsq[row] = ss;
}

// One block = one 128x128 tile of one distance matrix for one mc sample.
// K=128 processed in two K=64 phases through a single 32 KB LDS buffer
// (+1 KB staged sumsq) -> 4 blocks/CU instead of 2.
__global__ __launch_bounds__(256, 4) void dist_kernel(
    const unsigned short* __restrict__ Xb, const float* __restrict__ sumsq,
    float* __restrict__ out)
{
    const int tn = blockIdx.x >> 2, tk = blockIdx.x & 3;
    const int m = blockIdx.y;
    const int dist = blockIdx.z;
    // dist 0: AC (x=A=0, y=C=2); dist 1: BA (x=B=1, y=A=0); dist 2: BC (x=B=1, y=C=2)
    const int gx = (dist == 0) ? 0 : 1;
    const int gy = (dist == 1) ? 0 : 2;

    const unsigned short* Xa = Xb + (((size_t)(gx * 64 + m)) * 512 + tn * 128) * D;
    const unsigned short* Xc = Xb + (((size_t)(gy * 64 + m)) * 512 + tk * 128) * D;
    const float* ssx = sumsq + ((size_t)(gx * 64 + m)) * 512 + tn * 128;
    const float* ssy = sumsq + ((size_t)(gy * 64 + m)) * 512 + tk * 128;

    __shared__ unsigned short lds[2 * 128 * 64];   // 32 KB: As half-K, Bs half-K
    __shared__ float ss_s[256];                    // [0:128) x2 rows, [128:256) y2 rows
    unsigned short* As = lds;
    unsigned short* Bs = lds + 128 * 64;

    const int t = threadIdx.x;
    const int wave = t >> 6, lane = t & 63;
    const int wr = (wave >> 1) * 64;      // wave's 64x64 quadrant
    const int wc = (wave & 1) * 64;
    const int l15 = lane & 15, quad = lane >> 4;

    f32x4 acc[4][4] = {};

    // ---- phase 0: stage columns [0,64) ----
    #pragma unroll
    for (int i = 0; i < 4; i++) {
        int c = t + i * 256;          // granule 0..1023 (8 granules/row)
        int row = c >> 3, g = c & 7;
        int sg = g ^ (row & 7);
        *(uint4*)&As[row * 64 + sg * 8] = *(const uint4*)&Xa[row * D + g * 8];
        *(uint4*)&Bs[row * 64 + sg * 8] = *(const uint4*)&Xc[row * D + g * 8];
    }
    if (t < 32)            ((float4*)ss_s)[t]       = ((const float4*)ssx)[t];
    else if (t < 64)       ((float4*)ss_s)[t]       = ((const float4*)ssy)[t - 32];
    __syncthreads();

    #pragma unroll
    for (int kk = 0; kk < 2; kk++) {
        const int gidx = kk * 4 + quad;
        bf16x8 a[4], b[4];
        #pragma unroll
        for (int fr = 0; fr < 4; fr++) {
            int row = wr + fr * 16 + l15;
            a[fr] = *(bf16x8*)&As[row * 64 + (gidx ^ (row & 7)) * 8];
        }
        #pragma unroll
        for (int fc = 0; fc < 4; fc++) {
            int row = wc + fc * 16 + l15;
            b[fc] = *(bf16x8*)&Bs[row * 64 + (gidx ^ (row & 7)) * 8];
        }
        #pragma unroll
        for (int fr = 0; fr < 4; fr++)
            #pragma unroll
            for (int fc = 0; fc < 4; fc++)
                acc[fr][fc] = __builtin_amdgcn_mfma_f32_16x16x32_bf16(
                    a[fr], b[fc], acc[fr][fc], 0, 0, 0);
    }
    __syncthreads();

    // ---- phase 1: stage columns [64,128) ----
    #pragma unroll
    for (int i = 0; i < 4; i++) {
        int c = t + i * 256;
        int row = c >> 3, g = c & 7;
        int sg = g ^ (row & 7);
        *(uint4*)&As[row * 64 + sg * 8] = *(const uint4*)&Xa[row * D + 64 + g * 8];
        *(uint4*)&Bs[row * 64 + sg * 8] = *(const uint4*)&Xc[row * D + 64 + g * 8];
    }
    __syncthreads();

    #pragma unroll
    for (int kk = 0; kk < 2; kk++) {
        const int gidx = kk * 4 + quad;
        bf16x8 a[4], b[4];
        #pragma unroll
        for (int fr = 0; fr < 4; fr++) {
            int row = wr + fr * 16 + l15;
            a[fr] = *(bf16x8*)&As[row * 64 + (gidx ^ (row & 7)) * 8];
        }
        #pragma unroll
        for (int fc = 0; fc < 4; fc++) {
            int row = wc + fc * 16 + l15;
            b[fc] = *(bf16x8*)&Bs[row * 64 + (gidx ^ (row & 7)) * 8];
        }
        #pragma unroll
        for (int fr = 0; fr < 4; fr++)
            #pragma unroll
            for (int fc = 0; fc < 4; fc++)
                acc[fr][fc] = __builtin_amdgcn_mfma_f32_16x16x32_bf16(
                    a[fr], b[fc], acc[fr][fc], 0, 0, 0);
    }

    // ---- epilogue: d2 = x2 + y2 - 2*dot; C layout: col=lane&15, row=quad*4+i ----
    float lsum = 0.f;
    #pragma unroll
    for (int fc = 0; fc < 4; fc++) {
        float y2 = ss_s[128 + wc + fc * 16 + l15];
        #pragma unroll
        for (int fr = 0; fr < 4; fr++) {
            #pragma unroll
            for (int i = 0; i < 4; i++) {
                float x2 = ss_s[wr + fr * 16 + quad * 4 + i];
                float d2 = fmaxf(fmaf(-2.f, acc[fr][fc][i], x2 + y2), 1e-12f);
                if (dist == 0) {
                    lsum += d2;                               // mean(dAC^2)
                } else if (d2 < 4.f) {                        // relu(M - d), M=2
                    float td = 2.f - sqrtf(d2);
                    lsum += td * td;
                }
            }
        }
    }

    #pragma unroll
    for (int o = 32; o > 0; o >>= 1) lsum += __shfl_down(lsum, o, 64);
    __syncthreads();                      // tiles no longer needed; reuse LDS
    float* red = (float*)lds;
    if (lane == 0) red[wave] = lsum;
    __syncthreads();
    if (t == 0) {
        float bs = red[0] + red[1] + red[2] + red[3];
        atomicAdd(out, bs * INV_COUNT);
    }
}

extern "C" void kernel_launch(void* const* d_in, const int* in_sizes, int n_in,
                              void* d_out, int out_size, void* d_ws, size_t ws_size,
                              hipStream_t stream) {
    const float* mu    = (const float*)d_in[0];
    const float* sigma = (const float*)d_in[1];
    const float* epsA  = (const float*)d_in[2];
    const float* epsB  = (const float*)d_in[3];
    const float* epsC  = (const float*)d_in[4];
    float* out = (float*)d_out;

    unsigned short* Xb = (unsigned short*)d_ws;              // 25.17 MB bf16
    float* sumsq = (float*)((char*)d_ws + X_ELEMS * sizeof(unsigned short)); // 0.39 MB

    prep_kernel<<<NROW / 4, 256, 0, stream>>>(mu, sigma, epsA, epsB, epsC, Xb, sumsq, out);

    dim3 grid(16, 64, 3);
    dist_kernel<<<grid, 256, 0, stream>>>(Xb, sumsq, out);
}